// Round 7
// baseline (254.549 us; speedup 1.0000x reference)
//
#include <hip/hip_runtime.h>

// QLoRA NF4 forward: out[b,s,o] = 4.0 * sum_r (sum_i x[b,s,i]*W_A[r,i]) * W_B[o,r]
// B=4 S=2048 IN=4096 OUT=4096 R=8. All fp32.
//
// R10: DECOUPLED STREAMS. R6-R9 post-mortem: four structurally different
//  fused kernels all pin at ~90-104us / 2.2 TB/s, insensitive to occupancy
//  (16-38%) and per-wave load depth (2-12). Remaining untested axis: every
//  fused variant interleaves the HBM read stream (x), L2 weight stream, and
//  HBM write stream (out) in one in-order wave -> neither stream runs deep.
//  The harness fill proves 6.6 TB/s write-only at 8 VGPRs. Split:
//   - K1: x -> interm. PURE READ stream (output 256 KB). Wave owns 2 rows,
//     10 independent loads/iter, acc[2][8], ~80 VGPR, no LDS/barriers.
//     1024 blocks = 16 waves/CU offered.
//   - K2: interm -> out. PURE WRITE stream (reads: 256KB interm + 128KiB wBt,
//     both L2). interm in SGPRs via readfirstlane (R6-proven), NO
//     launch_bounds cap (R5 lesson: caps below body need -> spills).
//     2048 blocks, 4 rows each.
//  Tripwires: K2 WRITE_SIZE == 131072 KB exactly; K1 WRITE ~= 256 KB.
//  Decision rule: if K1+K2 also sum to ~90us with clean counters, ~2.2TB/s
//  is the platform floor for this pattern -> roofline.

static __device__ __constant__ float NF4_TBL[16] = {
    -1.0f, -0.6961928009986877f, -0.5250730514526367f, -0.39491748809814453f,
    -0.28444138169288635f, -0.18477343022823334f, -0.09105003625154495f, 0.0f,
    0.07958029955625534f, 0.16093020141124725f, 0.24611230194568634f,
    0.33791524171829224f, 0.44070982933044434f, 0.5626170039176941f,
    0.7229568362236328f, 1.0f};

__global__ void nf4_dequant_kernel(const int* __restrict__ codesA,
                                   const float* __restrict__ absA,
                                   const int* __restrict__ codesB,
                                   const float* __restrict__ absB,
                                   float* __restrict__ wA,    // [8][4096]
                                   float* __restrict__ wBt,   // [8][4096] transposed
                                   int n) {
    int id = blockIdx.x * blockDim.x + threadIdx.x;
    if (id < n) {
        wA[id] = NF4_TBL[codesA[id] & 15] * absA[id >> 6];
        // wBt output-linear: id = r*4096 + o. codes_B flat index = o*8 + r,
        // absmax_B index = (o*8+r)>>6 = o>>3 (r<8). Stores coalesced.
        const int r = id >> 12;
        const int o = id & 4095;
        wBt[id] = NF4_TBL[codesB[o * 8 + r] & 15] * absB[o >> 3];
    }
}

// K1: interm[row][r] = 4 * sum_i x[row][i] * wA[r][i].
// Pure read stream. Wave owns 2 rows end-to-end; no LDS, no barriers.
__global__ __launch_bounds__(256) void lora_a_kernel(
    const float* __restrict__ x,       // [8192][4096]
    const float* __restrict__ wA,      // [8][4096]
    float* __restrict__ interm) {      // [8192][8]
    const int lane = threadIdx.x & 63;
    const int wid  = blockIdx.x * 4 + (threadIdx.x >> 6);   // 0..4095
    const size_t row0 = (size_t)wid * 2;

    const float4* __restrict__ x0  = (const float4*)(x + row0 * 4096);
    const float4* __restrict__ x1  = x0 + 1024;
    const float4* __restrict__ wA4 = (const float4*)wA;

    float acc0[8], acc1[8];
    #pragma unroll
    for (int r = 0; r < 8; ++r) { acc0[r] = 0.f; acc1[r] = 0.f; }

    #pragma unroll 1
    for (int q = 0; q < 16; ++q) {
        const int idx = q * 64 + lane;            // coalesced; 10 indep loads
        const float4 a0 = x0[idx];
        const float4 a1 = x1[idx];
        #pragma unroll
        for (int r = 0; r < 8; ++r) {
            const float4 w = wA4[r * 1024 + idx]; // L2-resident broadcast
            acc0[r] += a0.x * w.x + a0.y * w.y + a0.z * w.z + a0.w * w.w;
            acc1[r] += a1.x * w.x + a1.y * w.y + a1.z * w.z + a1.w * w.w;
        }
    }

    #pragma unroll
    for (int r = 0; r < 8; ++r) {
        float v0 = acc0[r], v1 = acc1[r];
        #pragma unroll
        for (int off = 32; off > 0; off >>= 1) {
            v0 += __shfl_down(v0, off, 64);
            v1 += __shfl_down(v1, off, 64);
        }
        if (lane == 0) {
            interm[row0 * 8 + r]       = v0 * 4.0f;   // SCALING folded
            interm[(row0 + 1) * 8 + r] = v1 * 4.0f;
        }
    }
}

// K2: out[row][o] = sum_r interm[row][r] * wBt[r][o].
// Near-pure write stream (reads are L2: 256KB interm + 128KiB wBt).
// Block owns 4 rows; interm hoisted to SGPRs; coalesced float4 stores.
__global__ __launch_bounds__(256) void lora_b_kernel(
    const float* __restrict__ interm,  // [8192][8]
    const float* __restrict__ wBt,     // [8][4096]
    float* __restrict__ out) {         // [8192][4096]
    const int t    = threadIdx.x;
    const size_t row0 = (size_t)blockIdx.x * 4;

    // interm is block-uniform -> SGPRs via readfirstlane (v_fma free SGPR op)
    const float* __restrict__ ip = interm + row0 * 8;
    float ims[4][8];
    #pragma unroll
    for (int m = 0; m < 4; ++m)
        #pragma unroll
        for (int r = 0; r < 8; ++r)
            ims[m][r] = __int_as_float(
                __builtin_amdgcn_readfirstlane(__float_as_int(ip[m * 8 + r])));

    const float4* __restrict__ wt = (const float4*)wBt;   // [8][1024]
    float4* __restrict__ o4 = (float4*)(out + row0 * 4096);

    #pragma unroll 1
    for (int k = 0; k < 4; ++k) {
        const int og = t + 256 * k;                       // float4 col group
        float4 w[8];
        #pragma unroll
        for (int r = 0; r < 8; ++r) w[r] = wt[r * 1024 + og];  // L2 broadcast

        #pragma unroll
        for (int m = 0; m < 4; ++m) {
            float4 s;
            s.x = ims[m][0] * w[0].x + ims[m][1] * w[1].x + ims[m][2] * w[2].x
                + ims[m][3] * w[3].x + ims[m][4] * w[4].x + ims[m][5] * w[5].x
                + ims[m][6] * w[6].x + ims[m][7] * w[7].x;
            s.y = ims[m][0] * w[0].y + ims[m][1] * w[1].y + ims[m][2] * w[2].y
                + ims[m][3] * w[3].y + ims[m][4] * w[4].y + ims[m][5] * w[5].y
                + ims[m][6] * w[6].y + ims[m][7] * w[7].y;
            s.z = ims[m][0] * w[0].z + ims[m][1] * w[1].z + ims[m][2] * w[2].z
                + ims[m][3] * w[3].z + ims[m][4] * w[4].z + ims[m][5] * w[5].z
                + ims[m][6] * w[6].z + ims[m][7] * w[7].z;
            s.w = ims[m][0] * w[0].w + ims[m][1] * w[1].w + ims[m][2] * w[2].w
                + ims[m][3] * w[3].w + ims[m][4] * w[4].w + ims[m][5] * w[5].w
                + ims[m][6] * w[6].w + ims[m][7] * w[7].w;
            o4[m * 1024 + og] = s;                        // coalesced
        }
    }
}

extern "C" void kernel_launch(void* const* d_in, const int* in_sizes, int n_in,
                              void* d_out, int out_size, void* d_ws, size_t ws_size,
                              hipStream_t stream) {
    const float* x        = (const float*)d_in[0];
    const int*   codes_A  = (const int*)d_in[1];
    const float* absmax_A = (const float*)d_in[2];
    const int*   codes_B  = (const int*)d_in[3];
    const float* absmax_B = (const float*)d_in[4];
    float* out = (float*)d_out;

    constexpr int NW = 8 * 4096;                 // elements per factor
    float* wA     = (float*)d_ws;                // 128 KB
    float* wBt    = (float*)d_ws + NW;           // 128 KB (transposed)
    float* interm = (float*)d_ws + 2 * NW;       // 8192*8 fp32 = 256 KB

    nf4_dequant_kernel<<<(NW + 255) / 256, 256, 0, stream>>>(
        codes_A, absmax_A, codes_B, absmax_B, wA, wBt, NW);

    lora_a_kernel<<<1024, 256, 0, stream>>>(x, wA, interm);
    lora_b_kernel<<<2048, 256, 0, stream>>>(interm, wBt, out);
}